// Round 5
// baseline (483.528 us; speedup 1.0000x reference)
//
#include <hip/hip_runtime.h>

// Problem: B=16384, F=1024, H=64, D=256, TE=CE=4.
// I/O fp32; internal fp16 MFMA, fp32 accum. out = (outA,outS,outB) [3][B][256].
//
// R5: counted-vmcnt falsified (R0 116us plain vs R4 126us counted). l1's 90%
// stall is a concurrency shortage: grid 768 = 3 blocks/CU exactly. Fixes:
//  - l1: 64x128 tile -> 1536 blocks (~5-6/CU), 17KB LDS single-buffer, plain
//    __syncthreads 2-barrier loop (R0 structure), XCD-chunk swizzle so the
//    two col-blocks of one x row-panel share an XCD L2.
//  - l2: merged 3-output kernel: 12 distinct (gi,e) GEMMs computed ONCE
//    (vs 28 pair-uses), h staged to LDS once per block, W2 direct
//    global->reg ping-pong, zero barriers in the pair loop.
//  - pack: R3 coalesced transpose (unchanged).

#define BB 16384
#define FF 1024

typedef _Float16 f16;
typedef __fp16 h16x2 __attribute__((ext_vector_type(2)));   // cvt_pkrtz return type
typedef _Float16 f16x4 __attribute__((ext_vector_type(4)));
typedef _Float16 f16x8 __attribute__((ext_vector_type(8)));
typedef float f32x4 __attribute__((ext_vector_type(4)));

__device__ __forceinline__ void load_lds16(const void* g, void* l) {
    __builtin_amdgcn_global_load_lds(
        (const __attribute__((address_space(1))) unsigned int*)g,
        (__attribute__((address_space(3))) unsigned int*)l, 16, 0, 0);
}

__device__ __forceinline__ f16x8 pack8(float4 lo, float4 hi) {
    union { f16x8 v; h16x2 p[4]; } u;
    u.p[0] = __builtin_amdgcn_cvt_pkrtz(lo.x, lo.y);
    u.p[1] = __builtin_amdgcn_cvt_pkrtz(lo.z, lo.w);
    u.p[2] = __builtin_amdgcn_cvt_pkrtz(hi.x, hi.y);
    u.p[3] = __builtin_amdgcn_cvt_pkrtz(hi.z, hi.w);
    return u.v;
}

// ---------------------------------------------------------------------------
// Pack (coalesced transposes):
//   Wp[g][c=e*64+h][k] f16   from W1g[e][k][h]   (3 x 256 x 1024)
//   W2T[g][e][d][h]   f16    from W2g[e][h][d]   (3 x 4 x 256 x 64)
//   Gp[g][kt<32][c<16][kk<32] f16 from Wgg[kt*32+kk][c], zero-pad (3 x 16384)
// ---------------------------------------------------------------------------
__global__ __launch_bounds__(256) void pack_kernel(
    const float* __restrict__ W1A, const float* __restrict__ W1S, const float* __restrict__ W1B,
    const float* __restrict__ W2A, const float* __restrict__ W2S, const float* __restrict__ W2B,
    const float* __restrict__ WgA, const float* __restrict__ WgS, const float* __restrict__ WgB,
    f16* __restrict__ Wp, f16* __restrict__ W2T, f16* __restrict__ Gp)
{
    __shared__ float T[64 * 65];
    const int b = blockIdx.x, tid = threadIdx.x;

    if (b < 192) {               // Wp: transpose 64k x 64h tile of W1[e][k][h]
        int g = b >> 6, e = (b >> 4) & 3, k0 = (b & 15) * 64;
        const float* W1 = (g == 0) ? W1A : ((g == 1) ? W1S : W1B);
        const float* src = W1 + e * 65536 + k0 * 64;
#pragma unroll
        for (int r = 0; r < 4; ++r) {
            int slot = r * 256 + tid, kr = slot >> 4, h4 = slot & 15;
            float4 v = *(const float4*)(src + kr * 64 + h4 * 4);
            T[(h4 * 4 + 0) * 65 + kr] = v.x;
            T[(h4 * 4 + 1) * 65 + kr] = v.y;
            T[(h4 * 4 + 2) * 65 + kr] = v.z;
            T[(h4 * 4 + 3) * 65 + kr] = v.w;
        }
        __syncthreads();
        f16* dst = Wp + g * 262144 + e * 64 * 1024 + k0;
#pragma unroll
        for (int r = 0; r < 4; ++r) {
            int slot = r * 256 + tid, h = slot >> 4, k4 = slot & 15;
            f16x4 o;
            o[0] = (f16)T[h * 65 + k4 * 4 + 0];
            o[1] = (f16)T[h * 65 + k4 * 4 + 1];
            o[2] = (f16)T[h * 65 + k4 * 4 + 2];
            o[3] = (f16)T[h * 65 + k4 * 4 + 3];
            *(f16x4*)(dst + h * 1024 + k4 * 4) = o;
        }
    } else if (b < 240) {        // W2T: transpose 64h x 64d tile of W2[e][h][d]
        int bb = b - 192;
        int g = bb >> 4, e = (bb >> 2) & 3, d0 = (bb & 3) * 64;
        const float* W2 = (g == 0) ? W2A : ((g == 1) ? W2S : W2B);
        const float* src = W2 + e * 16384 + d0;
#pragma unroll
        for (int r = 0; r < 4; ++r) {
            int slot = r * 256 + tid, hr = slot >> 4, d4 = slot & 15;
            float4 v = *(const float4*)(src + hr * 256 + d4 * 4);
            T[(d4 * 4 + 0) * 65 + hr] = v.x;
            T[(d4 * 4 + 1) * 65 + hr] = v.y;
            T[(d4 * 4 + 2) * 65 + hr] = v.z;
            T[(d4 * 4 + 3) * 65 + hr] = v.w;
        }
        __syncthreads();
        f16* dst = W2T + (g * 4 + e) * 16384 + d0 * 64;
#pragma unroll
        for (int r = 0; r < 4; ++r) {
            int slot = r * 256 + tid, dl = slot >> 4, h4 = slot & 15;
            f16x4 o;
            o[0] = (f16)T[dl * 65 + h4 * 4 + 0];
            o[1] = (f16)T[dl * 65 + h4 * 4 + 1];
            o[2] = (f16)T[dl * 65 + h4 * 4 + 2];
            o[3] = (f16)T[dl * 65 + h4 * 4 + 3];
            *(f16x4*)(dst + dl * 64 + h4 * 4) = o;
        }
    } else {                     // Gp: [g][kt][c][kk]
        int g = b - 240;
        int ng = (g == 1) ? 12 : 8;
        const float* Wg = (g == 0) ? WgA : ((g == 1) ? WgS : WgB);
#pragma unroll 4
        for (int r = 0; r < 64; ++r) {
            int j = r * 256 + tid;            // 0..16383
            int kt = j >> 9, c = (j >> 5) & 15, kk = j & 31;
            Gp[g * 16384 + j] = (c < ng) ? (f16)Wg[(kt * 32 + kk) * ng + c] : (f16)0.0f;
        }
    }
}

// ---------------------------------------------------------------------------
// Layer-1: h_g = relu(x_g @ W1cat_g + b1_g) -> fp16 h [3][B][256], plus fused
// gate softmax on col-block 0. 64x128 tile, BK=32, 32 k-steps.
// grid (2,256,3) = 1536 blocks (~5-6/CU), block 256 (4 waves).
// Single-buffered LDS (17 KB), plain 2-barrier loop; XCD-chunk swizzle puts
// the two col-blocks of one row-panel on the same XCD.
// ---------------------------------------------------------------------------
__global__ __launch_bounds__(256, 4) void l1_kernel(
    const float* __restrict__ xA, const float* __restrict__ xS, const float* __restrict__ xB,
    const float* __restrict__ b1A, const float* __restrict__ b1S, const float* __restrict__ b1B,
    const float* __restrict__ bgA, const float* __restrict__ bgS, const float* __restrict__ bgB,
    const f16* __restrict__ Wp,      // [3][256][1024]
    const f16* __restrict__ Gp,      // [3][32][16][32]
    f16* __restrict__ hbuf,          // [3][B][256]
    float* __restrict__ gates)       // gA[B][8] | gS[B][12] | gB[B][8]
{
    // bijective XCD-chunk swizzle: nwg=1536, 8 XCDs, 192 per chunk.
    // dispatched id b -> logical (b&7)*192 + (b>>3); a (col0,col1) pair of the
    // same row-panel maps to dispatched ids 8 apart -> same XCD.
    int bid = blockIdx.x + (blockIdx.y << 1) + (blockIdx.z << 9);
    int logical = (bid & 7) * 192 + (bid >> 3);
    const int lx = logical & 1;
    const int row0 = ((logical >> 1) & 0xFF) * 64;
    const int g = logical >> 9;
    const int col0 = lx * 128;
    const bool do_gate = (lx == 0);

    const float* x  = (g == 0) ? xA  : ((g == 1) ? xS  : xB);
    const float* b1 = (g == 0) ? b1A : ((g == 1) ? b1S : b1B);
    const float* bg = (g == 0) ? bgA : ((g == 1) ? bgS : bgB);
    const int ng = (g == 1) ? 12 : 8;
    float* gout = gates + ((g == 0) ? (size_t)0
                         : (g == 1) ? (size_t)BB * 8
                                    : (size_t)BB * 8 + (size_t)BB * 12);

    __shared__ __align__(16) float Asf[64 * 32];    // fp32 x tile, swizzled segs
    __shared__ __align__(16) f16   Bsh[128 * 32];   // f16 W1 [n][k], swizzled
    __shared__ __align__(16) f16   Gs[512];         // gate tile [c=16][k=32]

    const int tid  = threadIdx.x;
    const int lane = tid & 63;
    const int wave = tid >> 6;
    const int wm = (wave >> 1) * 32;
    const int wn = (wave & 1) * 64;
    const int lrow = lane & 15;
    const int quad = lane >> 4;

    const f16* Wgrp = Wp + (size_t)g * 256 * 1024;
    const f16* Ggrp = Gp + (size_t)g * 16384;

    f32x4 acc[2][4] = {};
    f32x4 gacc[2] = {};
    const bool my_gate = do_gate && ((wave & 1) == 0);   // waves 0,2 (wn==0)

    for (int t = 0; t < 32; ++t) {
        const int k0 = t * 32;
        // stage x: 64 rows x 32 fp32 = 512 segs, 2/thread, seg^row swizzle
#pragma unroll
        for (int r = 0; r < 2; ++r) {
            int s = r * 256 + tid;
            int m = s >> 3, slot = s & 7;
            int seg = slot ^ (m & 7);
            load_lds16(x + (size_t)(row0 + m) * FF + k0 + seg * 4, Asf + s * 4);
        }
        // stage W1: 128 cols x 32k f16 = 512 segs, 2/thread
#pragma unroll
        for (int r = 0; r < 2; ++r) {
            int s = r * 256 + tid;
            int m = s >> 2, slot = s & 3;
            int seg = slot ^ ((m >> 1) & 3);
            load_lds16(Wgrp + (size_t)(col0 + m) * FF + k0 + seg * 8, Bsh + s * 8);
        }
        if (do_gate && tid < 64)
            load_lds16(Ggrp + (size_t)t * 512 + tid * 8, Gs + tid * 8);
        __syncthreads();    // compiler emits vmcnt(0) drain: tile visible

        f16x8 af[2], bfr[4];
#pragma unroll
        for (int i = 0; i < 2; ++i) {
            int m = wm + i * 16 + lrow;
            const float* rp = Asf + m * 32;
            int s0 = (2 * quad) ^ (m & 7);
            float4 lo = *(const float4*)(rp + s0 * 4);        // k=q*8..q*8+3
            float4 hi = *(const float4*)(rp + (s0 ^ 1) * 4);  // k=q*8+4..q*8+7
            af[i] = pack8(lo, hi);
        }
#pragma unroll
        for (int j = 0; j < 4; ++j) {
            int n = wn + j * 16 + lrow;
            int slot = quad ^ ((n >> 1) & 3);
            bfr[j] = *(const f16x8*)(Bsh + n * 32 + slot * 8);
        }
#pragma unroll
        for (int i = 0; i < 2; ++i)
#pragma unroll
            for (int j = 0; j < 4; ++j)
                acc[i][j] = __builtin_amdgcn_mfma_f32_16x16x32_f16(af[i], bfr[j], acc[i][j], 0, 0, 0);
        if (my_gate) {
            f16x8 gb = *(const f16x8*)(Gs + lrow * 32 + quad * 8);
#pragma unroll
            for (int i = 0; i < 2; ++i)
                gacc[i] = __builtin_amdgcn_mfma_f32_16x16x32_f16(af[i], gb, gacc[i], 0, 0, 0);
        }
        __syncthreads();    // readers done before next stage overwrites
    }

    // epilogue: h = relu(acc + b1) -> fp16. C/D: col=lane&15, row=quad*4+reg.
#pragma unroll
    for (int j = 0; j < 4; ++j) {
        int c = col0 + wn + j * 16 + lrow;
        float bias = b1[c];
#pragma unroll
        for (int i = 0; i < 2; ++i) {
#pragma unroll
            for (int r = 0; r < 4; ++r) {
                int row = row0 + wm + i * 16 + quad * 4 + r;
                float v = fmaxf(acc[i][j][r] + bias, 0.0f);
                hbuf[((size_t)g * BB + row) * 256 + c] = (f16)v;
            }
        }
    }

    // gate softmax: 16-lane groups share one row's logits (c = lrow)
    if (my_gate) {
        int c = lrow;
        bool valid = (c < ng);
        float bias = valid ? bg[c] : 0.0f;
#pragma unroll
        for (int i = 0; i < 2; ++i) {
#pragma unroll
            for (int r = 0; r < 4; ++r) {
                int row = row0 + wm + i * 16 + quad * 4 + r;
                float logit = valid ? (gacc[i][r] + bias) : -1e30f;
                float mx = logit;
#pragma unroll
                for (int m = 1; m < 16; m <<= 1)
                    mx = fmaxf(mx, __shfl_xor(mx, m, 16));
                float ev = valid ? __expf(logit - mx) : 0.0f;
                float sum = ev;
#pragma unroll
                for (int m = 1; m < 16; m <<= 1)
                    sum += __shfl_xor(sum, m, 16);
                if (valid) gout[(size_t)row * ng + c] = ev / sum;
            }
        }
    }
}

// ---------------------------------------------------------------------------
// Layer-2 merged: all 3 outputs per block. grid 512 (32 rows each), block 256.
// h[3][32][256] staged to LDS ONCE; each of 12 (gi,e) expert GEMMs computed
// once and folded into oA/oS/oB with its gates. W2 fragments direct
// global->reg ping-pong. No barriers in the pair loop.
// ---------------------------------------------------------------------------
__global__ __launch_bounds__(256, 2) void l2_kernel(
    const f16* __restrict__ hbuf,    // [3][B][256]
    const f16* __restrict__ W2T,     // [3][4][256][64]
    const float* __restrict__ b2A, const float* __restrict__ b2S, const float* __restrict__ b2B,
    const float* __restrict__ gates,
    float* __restrict__ out)         // [3][B][256] (A,S,B)
{
    extern __shared__ char smem[];
    f16*   hls = (f16*)smem;                 // [3][32][256] 49152 B, swizzled
    float* b2s = (float*)(smem + 49152);     // [3][1024]    12288 B
    float* gsh = (float*)(smem + 61440);     // [32][28]      3584 B

    const int row0 = blockIdx.x * 32;
    const int tid  = threadIdx.x;
    const int lane = tid & 63;
    const int w    = tid >> 6;
    const int lrow = lane & 15;
    const int quad = lane >> 4;
    const int wn2  = w * 64;                 // wave's d-quarter

    const float* gp0 = gates;
    const float* gp1 = gates + (size_t)BB * 8;
    const float* gp2 = gates + (size_t)BB * 8 + (size_t)BB * 12;

    // ---- one-time staging --------------------------------------------------
    // h slices: per gi, 32 rows x 256 f16 = 1024 segs of 16B, seg^row swizzle
#pragma unroll
    for (int gi = 0; gi < 3; ++gi) {
#pragma unroll
        for (int r = 0; r < 4; ++r) {
            int s = r * 256 + tid;
            int m = s >> 5, slot = s & 31;
            int seg = slot ^ (m & 7);
            load_lds16(hbuf + ((size_t)(gi * BB + row0 + m)) * 256 + seg * 8,
                       hls + gi * 8192 + s * 8);
        }
    }
    // biases
    load_lds16(b2A + tid * 4, b2s + tid * 4);
    load_lds16(b2S + tid * 4, b2s + 1024 + tid * 4);
    load_lds16(b2B + tid * 4, b2s + 2048 + tid * 4);
    // gates -> gsh[row][28]: gA 0-7 | gS 8-19 | gB 20-27
#pragma unroll
    for (int it = 0; it < 4; ++it) {
        int idx = it * 256 + tid;
        if (idx < 896) {
            int row = idx / 28, c = idx % 28;
            float v;
            if (c < 8)       v = gp0[(size_t)(row0 + row) * 8 + c];
            else if (c < 20) v = gp1[(size_t)(row0 + row) * 12 + (c - 8)];
            else             v = gp2[(size_t)(row0 + row) * 8 + (c - 20)];
            gsh[idx] = v;
        }
    }

    // W2 fragment issue: 8 b128 loads/thread per pair
    f16x8 wfA[2][4], wfB[2][4];
    auto issue_wf2 = [&](int p, f16x8 (&wf)[2][4]) {
        int gi = p >> 2, e = p & 3;
        const f16* w2 = W2T + (size_t)(gi * 4 + e) * 16384;
#pragma unroll
        for (int kk = 0; kk < 2; ++kk)
#pragma unroll
            for (int j = 0; j < 4; ++j)
                wf[kk][j] = *(const f16x8*)(w2 + (size_t)(wn2 + j * 16 + lrow) * 64 + kk * 32 + quad * 8);
    };

    issue_wf2(0, wfA);
    __syncthreads();   // h/b2/gates visible; LDS is read-only from here on

    f32x4 oA[2][4] = {}, oS[2][4] = {}, oB[2][4] = {};

    auto pair_step = [&](int p, f16x8 (&wfC)[2][4], f16x8 (&wfN)[2][4]) {
        if (p < 11) issue_wf2(p + 1, wfN);
        const int gi = p >> 2, e = p & 3;

        f32x4 eacc[2][4] = {};
#pragma unroll
        for (int kk = 0; kk < 2; ++kk) {
            f16x8 af[2];
#pragma unroll
            for (int i = 0; i < 2; ++i) {
                int rr = i * 16 + lrow;
                int slot = (e * 8 + kk * 4 + quad) ^ (rr & 7);
                af[i] = *(const f16x8*)(hls + gi * 8192 + rr * 256 + slot * 8);
            }
#pragma unroll
            for (int i = 0; i < 2; ++i)
#pragma unroll
                for (int j = 0; j < 4; ++j)
                    eacc[i][j] = __builtin_amdgcn_mfma_f32_16x16x32_f16(af[i], wfC[kk][j], eacc[i][j], 0, 0, 0);
        }

        float bias[4];
#pragma unroll
        for (int j = 0; j < 4; ++j)
            bias[j] = b2s[gi * 1024 + e * 256 + wn2 + j * 16 + lrow];

#pragma unroll
        for (int i = 0; i < 2; ++i) {
#pragma unroll
            for (int r = 0; r < 4; ++r) {
                int row = i * 16 + quad * 4 + r;
                float ga = 0.f, gs = 0.f, gb = 0.f;
                if (gi == 0)      { ga = gsh[row * 28 + e];      gs = gsh[row * 28 + 8 + e]; }
                else if (gi == 1) { ga = gsh[row * 28 + 4 + e];  gs = gsh[row * 28 + 12 + e]; gb = gsh[row * 28 + 24 + e]; }
                else              { gs = gsh[row * 28 + 16 + e]; gb = gsh[row * 28 + 20 + e]; }
#pragma unroll
                for (int j = 0; j < 4; ++j) {
                    float v = fmaxf(eacc[i][j][r] + bias[j], 0.0f);
                    if (gi == 0)      { oA[i][j][r] += ga * v; oS[i][j][r] += gs * v; }
                    else if (gi == 1) { oA[i][j][r] += ga * v; oS[i][j][r] += gs * v; oB[i][j][r] += gb * v; }
                    else              { oS[i][j][r] += gs * v; oB[i][j][r] += gb * v; }
                }
            }
        }
    };

#pragma unroll
    for (int pp = 0; pp < 6; ++pp) {
        pair_step(2 * pp, wfA, wfB);
        pair_step(2 * pp + 1, wfB, wfA);
    }

    // epilogue: write the three outputs
#pragma unroll
    for (int j = 0; j < 4; ++j) {
        int d = wn2 + j * 16 + lrow;
#pragma unroll
        for (int i = 0; i < 2; ++i) {
#pragma unroll
            for (int r = 0; r < 4; ++r) {
                int row = row0 + i * 16 + quad * 4 + r;
                out[((size_t)0 * BB + row) * 256 + d] = oA[i][j][r];
                out[((size_t)1 * BB + row) * 256 + d] = oS[i][j][r];
                out[((size_t)2 * BB + row) * 256 + d] = oB[i][j][r];
            }
        }
    }
}

// ---------------------------------------------------------------------------
extern "C" void kernel_launch(void* const* d_in, const int* in_sizes, int n_in,
                              void* d_out, int out_size, void* d_ws, size_t ws_size,
                              hipStream_t stream)
{
    (void)in_sizes; (void)n_in; (void)out_size; (void)ws_size;

    const float* xA  = (const float*)d_in[0];
    const float* xS  = (const float*)d_in[1];
    const float* xB  = (const float*)d_in[2];
    const float* W1A = (const float*)d_in[3];
    const float* b1A = (const float*)d_in[4];
    const float* W2A = (const float*)d_in[5];
    const float* b2A = (const float*)d_in[6];
    const float* W1S = (const float*)d_in[7];
    const float* b1S = (const float*)d_in[8];
    const float* W2S = (const float*)d_in[9];
    const float* b2S = (const float*)d_in[10];
    const float* W1B = (const float*)d_in[11];
    const float* b1B = (const float*)d_in[12];
    const float* W2B = (const float*)d_in[13];
    const float* b2B = (const float*)d_in[14];
    const float* WgA = (const float*)d_in[15];
    const float* bgA = (const float*)d_in[16];
    const float* WgB = (const float*)d_in[17];
    const float* bgB = (const float*)d_in[18];
    const float* WgS = (const float*)d_in[19];
    const float* bgS = (const float*)d_in[20];

    char* ws = (char*)d_ws;
    f16*   Wp   = (f16*)(ws);                       // 1,572,864 B
    f16*   W2T  = (f16*)(ws + 0x180000);            //   393,216 B
    f16*   Gp   = (f16*)(ws + 0x1E0000);            //    98,304 B
    f16*   hbuf = (f16*)(ws + 0x200000);            // 25,165,824 B
    float* gate = (float*)(ws + 0x200000 + 0x1800000); // 1,835,008 B

    pack_kernel<<<243, 256, 0, stream>>>(W1A, W1S, W1B, W2A, W2S, W2B,
                                         WgA, WgS, WgB, Wp, W2T, Gp);
    l1_kernel<<<dim3(2, 256, 3), 256, 0, stream>>>(
        xA, xS, xB, b1A, b1S, b1B, bgA, bgS, bgB,
        Wp, Gp, hbuf, gate);
    l2_kernel<<<512, 256, 65024, stream>>>(
        hbuf, W2T, b2A, b2S, b2B, gate, (float*)d_out);
}

// Round 6
// 437.741 us; speedup vs baseline: 1.1046x; 1.1046x over previous
//
#include <hip/hip_runtime.h>

// Problem: B=16384, F=1024, H=64, D=256, TE=CE=4.
// I/O fp32; internal fp16 MFMA, fp32 accum. out = (outA,outS,outB) [3][B][256].
//
// R6: R5's merged l2 spilled (WRITE 350MB, ~200 live regs vs 128 cap).
// Same dedup algorithm (12 distinct (gi,e) GEMMs, h staged once), restructured
// for register budget: 512 thr / 8 waves, each wave owns a 32-d quarter ->
// oA/oS/oB = 48 VGPR; no W2 ping-pong (L2 bubble hidden by 16 waves/CU TLP);
// __launch_bounds__(512,4) pins cap at 128, 2 blocks/CU.
// l1 and pack are UNCHANGED from R5 (so l2's delta is attributable and l1's
// R5-structure time becomes visible in top-5).

#define BB 16384
#define FF 1024

typedef _Float16 f16;
typedef __fp16 h16x2 __attribute__((ext_vector_type(2)));   // cvt_pkrtz return type
typedef _Float16 f16x4 __attribute__((ext_vector_type(4)));
typedef _Float16 f16x8 __attribute__((ext_vector_type(8)));
typedef float f32x4 __attribute__((ext_vector_type(4)));

__device__ __forceinline__ void load_lds16(const void* g, void* l) {
    __builtin_amdgcn_global_load_lds(
        (const __attribute__((address_space(1))) unsigned int*)g,
        (__attribute__((address_space(3))) unsigned int*)l, 16, 0, 0);
}

__device__ __forceinline__ f16x8 pack8(float4 lo, float4 hi) {
    union { f16x8 v; h16x2 p[4]; } u;
    u.p[0] = __builtin_amdgcn_cvt_pkrtz(lo.x, lo.y);
    u.p[1] = __builtin_amdgcn_cvt_pkrtz(lo.z, lo.w);
    u.p[2] = __builtin_amdgcn_cvt_pkrtz(hi.x, hi.y);
    u.p[3] = __builtin_amdgcn_cvt_pkrtz(hi.z, hi.w);
    return u.v;
}

// ---------------------------------------------------------------------------
// Pack (coalesced transposes) — unchanged from R5.
//   Wp[g][c=e*64+h][k] f16   from W1g[e][k][h]   (3 x 256 x 1024)
//   W2T[g][e][d][h]   f16    from W2g[e][h][d]   (3 x 4 x 256 x 64)
//   Gp[g][kt<32][c<16][kk<32] f16 from Wgg[kt*32+kk][c], zero-pad (3 x 16384)
// ---------------------------------------------------------------------------
__global__ __launch_bounds__(256) void pack_kernel(
    const float* __restrict__ W1A, const float* __restrict__ W1S, const float* __restrict__ W1B,
    const float* __restrict__ W2A, const float* __restrict__ W2S, const float* __restrict__ W2B,
    const float* __restrict__ WgA, const float* __restrict__ WgS, const float* __restrict__ WgB,
    f16* __restrict__ Wp, f16* __restrict__ W2T, f16* __restrict__ Gp)
{
    __shared__ float T[64 * 65];
    const int b = blockIdx.x, tid = threadIdx.x;

    if (b < 192) {               // Wp: transpose 64k x 64h tile of W1[e][k][h]
        int g = b >> 6, e = (b >> 4) & 3, k0 = (b & 15) * 64;
        const float* W1 = (g == 0) ? W1A : ((g == 1) ? W1S : W1B);
        const float* src = W1 + e * 65536 + k0 * 64;
#pragma unroll
        for (int r = 0; r < 4; ++r) {
            int slot = r * 256 + tid, kr = slot >> 4, h4 = slot & 15;
            float4 v = *(const float4*)(src + kr * 64 + h4 * 4);
            T[(h4 * 4 + 0) * 65 + kr] = v.x;
            T[(h4 * 4 + 1) * 65 + kr] = v.y;
            T[(h4 * 4 + 2) * 65 + kr] = v.z;
            T[(h4 * 4 + 3) * 65 + kr] = v.w;
        }
        __syncthreads();
        f16* dst = Wp + g * 262144 + e * 64 * 1024 + k0;
#pragma unroll
        for (int r = 0; r < 4; ++r) {
            int slot = r * 256 + tid, h = slot >> 4, k4 = slot & 15;
            f16x4 o;
            o[0] = (f16)T[h * 65 + k4 * 4 + 0];
            o[1] = (f16)T[h * 65 + k4 * 4 + 1];
            o[2] = (f16)T[h * 65 + k4 * 4 + 2];
            o[3] = (f16)T[h * 65 + k4 * 4 + 3];
            *(f16x4*)(dst + h * 1024 + k4 * 4) = o;
        }
    } else if (b < 240) {        // W2T: transpose 64h x 64d tile of W2[e][h][d]
        int bb = b - 192;
        int g = bb >> 4, e = (bb >> 2) & 3, d0 = (bb & 3) * 64;
        const float* W2 = (g == 0) ? W2A : ((g == 1) ? W2S : W2B);
        const float* src = W2 + e * 16384 + d0;
#pragma unroll
        for (int r = 0; r < 4; ++r) {
            int slot = r * 256 + tid, hr = slot >> 4, d4 = slot & 15;
            float4 v = *(const float4*)(src + hr * 256 + d4 * 4);
            T[(d4 * 4 + 0) * 65 + hr] = v.x;
            T[(d4 * 4 + 1) * 65 + hr] = v.y;
            T[(d4 * 4 + 2) * 65 + hr] = v.z;
            T[(d4 * 4 + 3) * 65 + hr] = v.w;
        }
        __syncthreads();
        f16* dst = W2T + (g * 4 + e) * 16384 + d0 * 64;
#pragma unroll
        for (int r = 0; r < 4; ++r) {
            int slot = r * 256 + tid, dl = slot >> 4, h4 = slot & 15;
            f16x4 o;
            o[0] = (f16)T[dl * 65 + h4 * 4 + 0];
            o[1] = (f16)T[dl * 65 + h4 * 4 + 1];
            o[2] = (f16)T[dl * 65 + h4 * 4 + 2];
            o[3] = (f16)T[dl * 65 + h4 * 4 + 3];
            *(f16x4*)(dst + dl * 64 + h4 * 4) = o;
        }
    } else {                     // Gp: [g][kt][c][kk]
        int g = b - 240;
        int ng = (g == 1) ? 12 : 8;
        const float* Wg = (g == 0) ? WgA : ((g == 1) ? WgS : WgB);
#pragma unroll 4
        for (int r = 0; r < 64; ++r) {
            int j = r * 256 + tid;            // 0..16383
            int kt = j >> 9, c = (j >> 5) & 15, kk = j & 31;
            Gp[g * 16384 + j] = (c < ng) ? (f16)Wg[(kt * 32 + kk) * ng + c] : (f16)0.0f;
        }
    }
}

// ---------------------------------------------------------------------------
// Layer-1 — unchanged from R5. 64x128 tile, BK=32, grid (2,256,3) = 1536
// blocks, block 256, single-buffer LDS, plain 2-barrier loop, XCD swizzle.
// ---------------------------------------------------------------------------
__global__ __launch_bounds__(256, 4) void l1_kernel(
    const float* __restrict__ xA, const float* __restrict__ xS, const float* __restrict__ xB,
    const float* __restrict__ b1A, const float* __restrict__ b1S, const float* __restrict__ b1B,
    const float* __restrict__ bgA, const float* __restrict__ bgS, const float* __restrict__ bgB,
    const f16* __restrict__ Wp,      // [3][256][1024]
    const f16* __restrict__ Gp,      // [3][32][16][32]
    f16* __restrict__ hbuf,          // [3][B][256]
    float* __restrict__ gates)       // gA[B][8] | gS[B][12] | gB[B][8]
{
    int bid = blockIdx.x + (blockIdx.y << 1) + (blockIdx.z << 9);
    int logical = (bid & 7) * 192 + (bid >> 3);
    const int lx = logical & 1;
    const int row0 = ((logical >> 1) & 0xFF) * 64;
    const int g = logical >> 9;
    const int col0 = lx * 128;
    const bool do_gate = (lx == 0);

    const float* x  = (g == 0) ? xA  : ((g == 1) ? xS  : xB);
    const float* b1 = (g == 0) ? b1A : ((g == 1) ? b1S : b1B);
    const float* bg = (g == 0) ? bgA : ((g == 1) ? bgS : bgB);
    const int ng = (g == 1) ? 12 : 8;
    float* gout = gates + ((g == 0) ? (size_t)0
                         : (g == 1) ? (size_t)BB * 8
                                    : (size_t)BB * 8 + (size_t)BB * 12);

    __shared__ __align__(16) float Asf[64 * 32];    // fp32 x tile, swizzled segs
    __shared__ __align__(16) f16   Bsh[128 * 32];   // f16 W1 [n][k], swizzled
    __shared__ __align__(16) f16   Gs[512];         // gate tile [c=16][k=32]

    const int tid  = threadIdx.x;
    const int lane = tid & 63;
    const int wave = tid >> 6;
    const int wm = (wave >> 1) * 32;
    const int wn = (wave & 1) * 64;
    const int lrow = lane & 15;
    const int quad = lane >> 4;

    const f16* Wgrp = Wp + (size_t)g * 256 * 1024;
    const f16* Ggrp = Gp + (size_t)g * 16384;

    f32x4 acc[2][4] = {};
    f32x4 gacc[2] = {};
    const bool my_gate = do_gate && ((wave & 1) == 0);

    for (int t = 0; t < 32; ++t) {
        const int k0 = t * 32;
#pragma unroll
        for (int r = 0; r < 2; ++r) {
            int s = r * 256 + tid;
            int m = s >> 3, slot = s & 7;
            int seg = slot ^ (m & 7);
            load_lds16(x + (size_t)(row0 + m) * FF + k0 + seg * 4, Asf + s * 4);
        }
#pragma unroll
        for (int r = 0; r < 2; ++r) {
            int s = r * 256 + tid;
            int m = s >> 2, slot = s & 3;
            int seg = slot ^ ((m >> 1) & 3);
            load_lds16(Wgrp + (size_t)(col0 + m) * FF + k0 + seg * 8, Bsh + s * 8);
        }
        if (do_gate && tid < 64)
            load_lds16(Ggrp + (size_t)t * 512 + tid * 8, Gs + tid * 8);
        __syncthreads();

        f16x8 af[2], bfr[4];
#pragma unroll
        for (int i = 0; i < 2; ++i) {
            int m = wm + i * 16 + lrow;
            const float* rp = Asf + m * 32;
            int s0 = (2 * quad) ^ (m & 7);
            float4 lo = *(const float4*)(rp + s0 * 4);
            float4 hi = *(const float4*)(rp + (s0 ^ 1) * 4);
            af[i] = pack8(lo, hi);
        }
#pragma unroll
        for (int j = 0; j < 4; ++j) {
            int n = wn + j * 16 + lrow;
            int slot = quad ^ ((n >> 1) & 3);
            bfr[j] = *(const f16x8*)(Bsh + n * 32 + slot * 8);
        }
#pragma unroll
        for (int i = 0; i < 2; ++i)
#pragma unroll
            for (int j = 0; j < 4; ++j)
                acc[i][j] = __builtin_amdgcn_mfma_f32_16x16x32_f16(af[i], bfr[j], acc[i][j], 0, 0, 0);
        if (my_gate) {
            f16x8 gb = *(const f16x8*)(Gs + lrow * 32 + quad * 8);
#pragma unroll
            for (int i = 0; i < 2; ++i)
                gacc[i] = __builtin_amdgcn_mfma_f32_16x16x32_f16(af[i], gb, gacc[i], 0, 0, 0);
        }
        __syncthreads();
    }

#pragma unroll
    for (int j = 0; j < 4; ++j) {
        int c = col0 + wn + j * 16 + lrow;
        float bias = b1[c];
#pragma unroll
        for (int i = 0; i < 2; ++i) {
#pragma unroll
            for (int r = 0; r < 4; ++r) {
                int row = row0 + wm + i * 16 + quad * 4 + r;
                float v = fmaxf(acc[i][j][r] + bias, 0.0f);
                hbuf[((size_t)g * BB + row) * 256 + c] = (f16)v;
            }
        }
    }

    if (my_gate) {
        int c = lrow;
        bool valid = (c < ng);
        float bias = valid ? bg[c] : 0.0f;
#pragma unroll
        for (int i = 0; i < 2; ++i) {
#pragma unroll
            for (int r = 0; r < 4; ++r) {
                int row = row0 + wm + i * 16 + quad * 4 + r;
                float logit = valid ? (gacc[i][r] + bias) : -1e30f;
                float mx = logit;
#pragma unroll
                for (int m = 1; m < 16; m <<= 1)
                    mx = fmaxf(mx, __shfl_xor(mx, m, 16));
                float ev = valid ? __expf(logit - mx) : 0.0f;
                float sum = ev;
#pragma unroll
                for (int m = 1; m < 16; m <<= 1)
                    sum += __shfl_xor(sum, m, 16);
                if (valid) gout[(size_t)row * ng + c] = ev / sum;
            }
        }
    }
}

// ---------------------------------------------------------------------------
// Layer-2 merged, register-budgeted. grid 512 (32 rows each), block 512
// (8 waves); wave w owns d-quarter wn2 = w*32. 12 distinct (gi,e) GEMMs
// computed once; h[3][32][256] staged once; W2 frags direct global->reg
// (no ping-pong; L2 bubble hidden by 16 waves/CU). No barriers in pair loop.
// Accums: oA/oS/oB = 3 x [2][2] f32x4 = 48 VGPR.
// ---------------------------------------------------------------------------
__global__ __launch_bounds__(512, 4) void l2_kernel(
    const f16* __restrict__ hbuf,    // [3][B][256]
    const f16* __restrict__ W2T,     // [3][4][256][64]
    const float* __restrict__ b2A, const float* __restrict__ b2S, const float* __restrict__ b2B,
    const float* __restrict__ gates,
    float* __restrict__ out)         // [3][B][256] (A,S,B)
{
    extern __shared__ char smem[];
    f16*   hls = (f16*)smem;                 // [3][32][256] 49152 B, swizzled
    float* b2s = (float*)(smem + 49152);     // [3][1024]    12288 B
    float* gsh = (float*)(smem + 61440);     // [32][28]      3584 B

    const int row0 = blockIdx.x * 32;
    const int tid  = threadIdx.x;
    const int lane = tid & 63;
    const int w    = tid >> 6;
    const int lrow = lane & 15;
    const int quad = lane >> 4;
    const int wn2  = w * 32;                 // wave's 32-d slice of 256

    const float* gp0 = gates;
    const float* gp1 = gates + (size_t)BB * 8;
    const float* gp2 = gates + (size_t)BB * 8 + (size_t)BB * 12;

    // ---- one-time staging ----------------------------------------------
    // h slices: per gi, 1024 segs of 16B (2/thread), seg^row swizzle
#pragma unroll
    for (int gi = 0; gi < 3; ++gi) {
#pragma unroll
        for (int r = 0; r < 2; ++r) {
            int s = r * 512 + tid;
            int m = s >> 5, slot = s & 31;
            int seg = slot ^ (m & 7);
            load_lds16(hbuf + ((size_t)(gi * BB + row0 + m)) * 256 + seg * 8,
                       hls + gi * 8192 + s * 8);
        }
    }
    // biases (wave-granular guards keep load_lds dest = wave base + lane*16)
    if (w < 4) load_lds16(b2A + tid * 4, b2s + tid * 4);
    else       load_lds16(b2S + (tid - 256) * 4, b2s + 1024 + (tid - 256) * 4);
    if (w < 4) load_lds16(b2B + tid * 4, b2s + 2048 + tid * 4);
    // gates -> gsh[row][28]: gA 0-7 | gS 8-19 | gB 20-27
#pragma unroll
    for (int it = 0; it < 2; ++it) {
        int idx = it * 512 + tid;
        if (idx < 896) {
            int row = idx / 28, c = idx % 28;
            float v;
            if (c < 8)       v = gp0[(size_t)(row0 + row) * 8 + c];
            else if (c < 20) v = gp1[(size_t)(row0 + row) * 12 + (c - 8)];
            else             v = gp2[(size_t)(row0 + row) * 8 + (c - 20)];
            gsh[idx] = v;
        }
    }

    __syncthreads();   // h/b2/gates visible; LDS read-only from here on

    f32x4 oA[2][2] = {}, oS[2][2] = {}, oB[2][2] = {};

#pragma unroll
    for (int p = 0; p < 12; ++p) {
        const int gi = p >> 2, e = p & 3;

        // W2 fragments for this pair: wave's 32 d x 64 h (4 b128 loads)
        f16x8 wf[2][2];
        const f16* w2 = W2T + (size_t)(gi * 4 + e) * 16384;
#pragma unroll
        for (int kk = 0; kk < 2; ++kk)
#pragma unroll
            for (int j = 0; j < 2; ++j)
                wf[kk][j] = *(const f16x8*)(w2 + (size_t)(wn2 + j * 16 + lrow) * 64 + kk * 32 + quad * 8);

        f32x4 eacc[2][2] = {};
#pragma unroll
        for (int kk = 0; kk < 2; ++kk) {
            f16x8 af[2];
#pragma unroll
            for (int i = 0; i < 2; ++i) {
                int rr = i * 16 + lrow;
                int slot = (e * 8 + kk * 4 + quad) ^ (rr & 7);
                af[i] = *(const f16x8*)(hls + gi * 8192 + rr * 256 + slot * 8);
            }
#pragma unroll
            for (int i = 0; i < 2; ++i)
#pragma unroll
                for (int j = 0; j < 2; ++j)
                    eacc[i][j] = __builtin_amdgcn_mfma_f32_16x16x32_f16(af[i], wf[kk][j], eacc[i][j], 0, 0, 0);
        }

        float bias[2];
#pragma unroll
        for (int j = 0; j < 2; ++j)
            bias[j] = b2s[gi * 1024 + e * 256 + wn2 + j * 16 + lrow];

#pragma unroll
        for (int i = 0; i < 2; ++i) {
#pragma unroll
            for (int r = 0; r < 4; ++r) {
                int row = i * 16 + quad * 4 + r;
                float ga = 0.f, gs = 0.f, gb = 0.f;
                if (gi == 0)      { ga = gsh[row * 28 + e];      gs = gsh[row * 28 + 8 + e]; }
                else if (gi == 1) { ga = gsh[row * 28 + 4 + e];  gs = gsh[row * 28 + 12 + e]; gb = gsh[row * 28 + 24 + e]; }
                else              { gs = gsh[row * 28 + 16 + e]; gb = gsh[row * 28 + 20 + e]; }
#pragma unroll
                for (int j = 0; j < 2; ++j) {
                    float v = fmaxf(eacc[i][j][r] + bias[j], 0.0f);
                    if (gi == 0)      { oA[i][j][r] += ga * v; oS[i][j][r] += gs * v; }
                    else if (gi == 1) { oA[i][j][r] += ga * v; oS[i][j][r] += gs * v; oB[i][j][r] += gb * v; }
                    else              { oS[i][j][r] += gs * v; oB[i][j][r] += gb * v; }
                }
            }
        }
    }

    // epilogue: write the three outputs
#pragma unroll
    for (int j = 0; j < 2; ++j) {
        int d = wn2 + j * 16 + lrow;
#pragma unroll
        for (int i = 0; i < 2; ++i) {
#pragma unroll
            for (int r = 0; r < 4; ++r) {
                int row = row0 + i * 16 + quad * 4 + r;
                out[((size_t)0 * BB + row) * 256 + d] = oA[i][j][r];
                out[((size_t)1 * BB + row) * 256 + d] = oS[i][j][r];
                out[((size_t)2 * BB + row) * 256 + d] = oB[i][j][r];
            }
        }
    }
}

// ---------------------------------------------------------------------------
extern "C" void kernel_launch(void* const* d_in, const int* in_sizes, int n_in,
                              void* d_out, int out_size, void* d_ws, size_t ws_size,
                              hipStream_t stream)
{
    (void)in_sizes; (void)n_in; (void)out_size; (void)ws_size;

    const float* xA  = (const float*)d_in[0];
    const float* xS  = (const float*)d_in[1];
    const float* xB  = (const float*)d_in[2];
    const float* W1A = (const float*)d_in[3];
    const float* b1A = (const float*)d_in[4];
    const float* W2A = (const float*)d_in[5];
    const float* b2A = (const float*)d_in[6];
    const float* W1S = (const float*)d_in[7];
    const float* b1S = (const float*)d_in[8];
    const float* W2S = (const float*)d_in[9];
    const float* b2S = (const float*)d_in[10];
    const float* W1B = (const float*)d_in[11];
    const float* b1B = (const float*)d_in[12];
    const float* W2B = (const float*)d_in[13];
    const float* b2B = (const float*)d_in[14];
    const float* WgA = (const float*)d_in[15];
    const float* bgA = (const float*)d_in[16];
    const float* WgB = (const float*)d_in[17];
    const float* bgB = (const float*)d_in[18];
    const float* WgS = (const float*)d_in[19];
    const float* bgS = (const float*)d_in[20];

    char* ws = (char*)d_ws;
    f16*   Wp   = (f16*)(ws);                       // 1,572,864 B
    f16*   W2T  = (f16*)(ws + 0x180000);            //   393,216 B
    f16*   Gp   = (f16*)(ws + 0x1E0000);            //    98,304 B
    f16*   hbuf = (f16*)(ws + 0x200000);            // 25,165,824 B
    float* gate = (float*)(ws + 0x200000 + 0x1800000); // 1,835,008 B

    pack_kernel<<<243, 256, 0, stream>>>(W1A, W1S, W1B, W2A, W2S, W2B,
                                         WgA, WgS, WgB, Wp, W2T, Gp);
    l1_kernel<<<dim3(2, 256, 3), 256, 0, stream>>>(
        xA, xS, xB, b1A, b1S, b1B, bgA, bgS, bgB,
        Wp, Gp, hbuf, gate);
    l2_kernel<<<512, 512, 65024, stream>>>(
        hbuf, W2T, b2A, b2S, b2B, gate, (float*)d_out);
}

// Round 7
// 345.609 us; speedup vs baseline: 1.3991x; 1.2666x over previous
//
#include <hip/hip_runtime.h>

// Problem: B=16384, F=1024, H=64, D=256, TE=CE=4.
// I/O fp32; internal fp16 MFMA, fp32 accum. out = (outA,outS,outB) [3][B][256].
//
// R7:
//  - l2 (merged dedup, 12 distinct GEMMs): fix the spill. R6's launch_bounds
//    (512,4) gave a 64-VGPR cap (arg acted as blocks/CU) -> 250MB scratch.
//    Now __launch_bounds__(512,2) (cap >=128 either semantics) + rolled pair
//    loop (#pragma unroll 1) to keep liveness ~104 VGPR.
//  - l1: restore R0's best-measured 128x128 single-buffer structure (116us),
//    + async 1-inst gate-tile staging (R5-verified, removes per-step gate
//    stall on col-block-0) + bijective 768=8x96 XCD-chunk swizzle (x / W1
//    panel reuse in same-XCD L2).
//  - pack unchanged (R3 coalesced transpose).

#define BB 16384
#define FF 1024

typedef _Float16 f16;
typedef __fp16 h16x2 __attribute__((ext_vector_type(2)));   // cvt_pkrtz return type
typedef _Float16 f16x4 __attribute__((ext_vector_type(4)));
typedef _Float16 f16x8 __attribute__((ext_vector_type(8)));
typedef float f32x4 __attribute__((ext_vector_type(4)));

__device__ __forceinline__ void load_lds16(const void* g, void* l) {
    __builtin_amdgcn_global_load_lds(
        (const __attribute__((address_space(1))) unsigned int*)g,
        (__attribute__((address_space(3))) unsigned int*)l, 16, 0, 0);
}

__device__ __forceinline__ f16x8 pack8(float4 lo, float4 hi) {
    union { f16x8 v; h16x2 p[4]; } u;
    u.p[0] = __builtin_amdgcn_cvt_pkrtz(lo.x, lo.y);
    u.p[1] = __builtin_amdgcn_cvt_pkrtz(lo.z, lo.w);
    u.p[2] = __builtin_amdgcn_cvt_pkrtz(hi.x, hi.y);
    u.p[3] = __builtin_amdgcn_cvt_pkrtz(hi.z, hi.w);
    return u.v;
}

// ---------------------------------------------------------------------------
// Pack (coalesced transposes):
//   Wp[g][c=e*64+h][k] f16   from W1g[e][k][h]   (3 x 256 x 1024)
//   W2T[g][e][d][h]   f16    from W2g[e][h][d]   (3 x 4 x 256 x 64)
//   Gp[g][kt<32][c<16][kk<32] f16 from Wgg[kt*32+kk][c], zero-pad (3 x 16384)
// ---------------------------------------------------------------------------
__global__ __launch_bounds__(256) void pack_kernel(
    const float* __restrict__ W1A, const float* __restrict__ W1S, const float* __restrict__ W1B,
    const float* __restrict__ W2A, const float* __restrict__ W2S, const float* __restrict__ W2B,
    const float* __restrict__ WgA, const float* __restrict__ WgS, const float* __restrict__ WgB,
    f16* __restrict__ Wp, f16* __restrict__ W2T, f16* __restrict__ Gp)
{
    __shared__ float T[64 * 65];
    const int b = blockIdx.x, tid = threadIdx.x;

    if (b < 192) {               // Wp: transpose 64k x 64h tile of W1[e][k][h]
        int g = b >> 6, e = (b >> 4) & 3, k0 = (b & 15) * 64;
        const float* W1 = (g == 0) ? W1A : ((g == 1) ? W1S : W1B);
        const float* src = W1 + e * 65536 + k0 * 64;
#pragma unroll
        for (int r = 0; r < 4; ++r) {
            int slot = r * 256 + tid, kr = slot >> 4, h4 = slot & 15;
            float4 v = *(const float4*)(src + kr * 64 + h4 * 4);
            T[(h4 * 4 + 0) * 65 + kr] = v.x;
            T[(h4 * 4 + 1) * 65 + kr] = v.y;
            T[(h4 * 4 + 2) * 65 + kr] = v.z;
            T[(h4 * 4 + 3) * 65 + kr] = v.w;
        }
        __syncthreads();
        f16* dst = Wp + g * 262144 + e * 64 * 1024 + k0;
#pragma unroll
        for (int r = 0; r < 4; ++r) {
            int slot = r * 256 + tid, h = slot >> 4, k4 = slot & 15;
            f16x4 o;
            o[0] = (f16)T[h * 65 + k4 * 4 + 0];
            o[1] = (f16)T[h * 65 + k4 * 4 + 1];
            o[2] = (f16)T[h * 65 + k4 * 4 + 2];
            o[3] = (f16)T[h * 65 + k4 * 4 + 3];
            *(f16x4*)(dst + h * 1024 + k4 * 4) = o;
        }
    } else if (b < 240) {        // W2T: transpose 64h x 64d tile of W2[e][h][d]
        int bb = b - 192;
        int g = bb >> 4, e = (bb >> 2) & 3, d0 = (bb & 3) * 64;
        const float* W2 = (g == 0) ? W2A : ((g == 1) ? W2S : W2B);
        const float* src = W2 + e * 16384 + d0;
#pragma unroll
        for (int r = 0; r < 4; ++r) {
            int slot = r * 256 + tid, hr = slot >> 4, d4 = slot & 15;
            float4 v = *(const float4*)(src + hr * 256 + d4 * 4);
            T[(d4 * 4 + 0) * 65 + hr] = v.x;
            T[(d4 * 4 + 1) * 65 + hr] = v.y;
            T[(d4 * 4 + 2) * 65 + hr] = v.z;
            T[(d4 * 4 + 3) * 65 + hr] = v.w;
        }
        __syncthreads();
        f16* dst = W2T + (g * 4 + e) * 16384 + d0 * 64;
#pragma unroll
        for (int r = 0; r < 4; ++r) {
            int slot = r * 256 + tid, dl = slot >> 4, h4 = slot & 15;
            f16x4 o;
            o[0] = (f16)T[dl * 65 + h4 * 4 + 0];
            o[1] = (f16)T[dl * 65 + h4 * 4 + 1];
            o[2] = (f16)T[dl * 65 + h4 * 4 + 2];
            o[3] = (f16)T[dl * 65 + h4 * 4 + 3];
            *(f16x4*)(dst + dl * 64 + h4 * 4) = o;
        }
    } else {                     // Gp: [g][kt][c][kk]
        int g = b - 240;
        int ng = (g == 1) ? 12 : 8;
        const float* Wg = (g == 0) ? WgA : ((g == 1) ? WgS : WgB);
#pragma unroll 4
        for (int r = 0; r < 64; ++r) {
            int j = r * 256 + tid;            // 0..16383
            int kt = j >> 9, c = (j >> 5) & 15, kk = j & 31;
            Gp[g * 16384 + j] = (c < ng) ? (f16)Wg[(kt * 32 + kk) * ng + c] : (f16)0.0f;
        }
    }
}

// ---------------------------------------------------------------------------
// Layer-1: h_g = relu(x_g @ W1cat_g + b1_g) -> fp16 h [3][B][256], plus fused
// gate softmax on col-block 0. 128x128 tile, BK=32, 32 k-steps.
// grid (2,128,3) = 768 blocks, block 256. R0 structure: single-buffer LDS,
// plain 2-barrier loop. New: async gate-tile staging, XCD-chunk swizzle
// (768 = 8 x 96; pair (col0,col1) and consecutive row-panels share an XCD).
// ---------------------------------------------------------------------------
__global__ __launch_bounds__(256) void l1_kernel(
    const float* __restrict__ xA, const float* __restrict__ xS, const float* __restrict__ xB,
    const float* __restrict__ b1A, const float* __restrict__ b1S, const float* __restrict__ b1B,
    const float* __restrict__ bgA, const float* __restrict__ bgS, const float* __restrict__ bgB,
    const f16* __restrict__ Wp,      // [3][256][1024]
    const f16* __restrict__ Gp,      // [3][32][16][32]
    f16* __restrict__ hbuf,          // [3][B][256]
    float* __restrict__ gates)       // gA[B][8] | gS[B][12] | gB[B][8]
{
    // bijective XCD-chunk swizzle: 768 blocks = 8 XCDs x 96.
    int bid = blockIdx.x + (blockIdx.y << 1) + (blockIdx.z << 8);
    int logical = (bid & 7) * 96 + (bid >> 3);
    const int lx   = logical & 1;
    const int row0 = ((logical >> 1) & 127) * 128;
    const int g    = logical >> 8;
    const int col0 = lx * 128;
    const bool do_gate = (lx == 0);

    const float* x  = (g == 0) ? xA  : ((g == 1) ? xS  : xB);
    const float* b1 = (g == 0) ? b1A : ((g == 1) ? b1S : b1B);
    const float* bg = (g == 0) ? bgA : ((g == 1) ? bgS : bgB);
    const int ng = (g == 1) ? 12 : 8;
    float* gout = gates + ((g == 0) ? (size_t)0
                         : (g == 1) ? (size_t)BB * 8
                                    : (size_t)BB * 8 + (size_t)BB * 12);

    __shared__ __align__(16) float Asf[128 * 32];   // fp32 x tile, swizzled segs
    __shared__ __align__(16) f16   Bsh[128 * 32];   // f16 W1 [n][k], swizzled
    __shared__ __align__(16) f16   Gs[512];         // gate tile [c=16][k=32]

    const int tid  = threadIdx.x;
    const int lane = tid & 63;
    const int wave = tid >> 6;
    const int wm = (wave >> 1) * 64;
    const int wn = (wave & 1) * 64;
    const int lrow = lane & 15;
    const int quad = lane >> 4;

    const f16* Wgrp = Wp + (size_t)g * 256 * 1024;
    const f16* Ggrp = Gp + (size_t)g * 16384;

    f32x4 acc[4][4] = {};
    f32x4 gacc[4] = {};
    const bool my_gate = do_gate && ((wave & 1) == 0);

    for (int t = 0; t < 32; ++t) {
        const int k0 = t * 32;
        // A: 1024 segs (16 KB fp32), 4 rounds. seg stored at slot = seg^(m&7).
#pragma unroll
        for (int r = 0; r < 4; ++r) {
            int s = r * 256 + tid;
            int m = s >> 3, slot = s & 7;
            int seg = slot ^ (m & 7);
            load_lds16(x + (size_t)(row0 + m) * FF + k0 + seg * 4, Asf + s * 4);
        }
        // B: 512 segs (8 KB f16), 2 rounds. slot = seg^((m>>1)&3).
#pragma unroll
        for (int r = 0; r < 2; ++r) {
            int s = r * 256 + tid;
            int m = s >> 2, slot = s & 3;
            int seg = slot ^ ((m >> 1) & 3);
            load_lds16(Wgrp + (size_t)(col0 + m) * FF + k0 + seg * 8, Bsh + s * 8);
        }
        // gate tile: 1 KB contiguous, async, 1 inst (wave 0 lanes only)
        if (do_gate && tid < 64)
            load_lds16(Ggrp + (size_t)t * 512 + tid * 8, Gs + tid * 8);
        __syncthreads();

        f16x8 af[4], bfr[4];
#pragma unroll
        for (int i = 0; i < 4; ++i) {
            int m = wm + i * 16 + lrow;
            const float* rp = Asf + m * 32;
            int s0 = (2 * quad) ^ (m & 7);
            int s1 = s0 ^ 1;
            float4 lo = *(const float4*)(rp + s0 * 4);   // k = q*8 .. q*8+3
            float4 hi = *(const float4*)(rp + s1 * 4);   // k = q*8+4 .. q*8+7
            af[i] = pack8(lo, hi);
        }
#pragma unroll
        for (int j = 0; j < 4; ++j) {
            int n = wn + j * 16 + lrow;
            int slot = quad ^ ((n >> 1) & 3);
            bfr[j] = *(const f16x8*)(Bsh + n * 32 + slot * 8);
        }
#pragma unroll
        for (int i = 0; i < 4; ++i)
#pragma unroll
            for (int j = 0; j < 4; ++j)
                acc[i][j] = __builtin_amdgcn_mfma_f32_16x16x32_f16(af[i], bfr[j], acc[i][j], 0, 0, 0);
        if (my_gate) {
            f16x8 gb = *(const f16x8*)(Gs + lrow * 32 + quad * 8);
#pragma unroll
            for (int i = 0; i < 4; ++i)
                gacc[i] = __builtin_amdgcn_mfma_f32_16x16x32_f16(af[i], gb, gacc[i], 0, 0, 0);
        }
        __syncthreads();
    }

    // epilogue: h = relu(acc + b1), fp16. C/D: col=lane&15, row=quad*4+reg.
#pragma unroll
    for (int j = 0; j < 4; ++j) {
        int c = col0 + wn + j * 16 + lrow;
        float bias = b1[c];
#pragma unroll
        for (int i = 0; i < 4; ++i) {
#pragma unroll
            for (int r = 0; r < 4; ++r) {
                int row = row0 + wm + i * 16 + quad * 4 + r;
                float v = fmaxf(acc[i][j][r] + bias, 0.0f);
                hbuf[((size_t)g * BB + row) * 256 + c] = (f16)v;
            }
        }
    }

    // gate softmax: 16-lane groups share one row's logits (c = lrow)
    if (my_gate) {
        int c = lrow;
        bool valid = (c < ng);
        float bias = valid ? bg[c] : 0.0f;
#pragma unroll
        for (int i = 0; i < 4; ++i) {
#pragma unroll
            for (int r = 0; r < 4; ++r) {
                int row = row0 + wm + i * 16 + quad * 4 + r;
                float logit = valid ? (gacc[i][r] + bias) : -1e30f;
                float mx = logit;
#pragma unroll
                for (int m = 1; m < 16; m <<= 1)
                    mx = fmaxf(mx, __shfl_xor(mx, m, 16));
                float ev = valid ? __expf(logit - mx) : 0.0f;
                float sum = ev;
#pragma unroll
                for (int m = 1; m < 16; m <<= 1)
                    sum += __shfl_xor(sum, m, 16);
                if (valid) gout[(size_t)row * ng + c] = ev / sum;
            }
        }
    }
}

// ---------------------------------------------------------------------------
// Layer-2 merged. grid 512 (32 rows each), block 512 (8 waves, wave owns a
// 32-d slice). 12 distinct (gi,e) GEMMs computed once; h staged once; W2
// frags direct global->reg; no barriers in the ROLLED pair loop (unroll 1
// keeps liveness ~104 VGPR). __launch_bounds__(512,2) -> cap >=128.
// ---------------------------------------------------------------------------
__global__ __launch_bounds__(512, 2) void l2_kernel(
    const f16* __restrict__ hbuf,    // [3][B][256]
    const f16* __restrict__ W2T,     // [3][4][256][64]
    const float* __restrict__ b2A, const float* __restrict__ b2S, const float* __restrict__ b2B,
    const float* __restrict__ gates,
    float* __restrict__ out)         // [3][B][256] (A,S,B)
{
    extern __shared__ char smem[];
    f16*   hls = (f16*)smem;                 // [3][32][256] 49152 B, swizzled
    float* b2s = (float*)(smem + 49152);     // [3][1024]    12288 B
    float* gsh = (float*)(smem + 61440);     // [32][28]      3584 B

    const int row0 = blockIdx.x * 32;
    const int tid  = threadIdx.x;
    const int lane = tid & 63;
    const int w    = tid >> 6;
    const int lrow = lane & 15;
    const int quad = lane >> 4;
    const int wn2  = w * 32;                 // wave's 32-d slice of 256

    const float* gp0 = gates;
    const float* gp1 = gates + (size_t)BB * 8;
    const float* gp2 = gates + (size_t)BB * 8 + (size_t)BB * 12;

    // ---- one-time staging ----------------------------------------------
#pragma unroll
    for (int gi = 0; gi < 3; ++gi) {
#pragma unroll
        for (int r = 0; r < 2; ++r) {
            int s = r * 512 + tid;
            int m = s >> 5, slot = s & 31;
            int seg = slot ^ (m & 7);
            load_lds16(hbuf + ((size_t)(gi * BB + row0 + m)) * 256 + seg * 8,
                       hls + gi * 8192 + s * 8);
        }
    }
    if (w < 4) load_lds16(b2A + tid * 4, b2s + tid * 4);
    else       load_lds16(b2S + (tid - 256) * 4, b2s + 1024 + (tid - 256) * 4);
    if (w < 4) load_lds16(b2B + tid * 4, b2s + 2048 + tid * 4);
#pragma unroll
    for (int it = 0; it < 2; ++it) {
        int idx = it * 512 + tid;
        if (idx < 896) {
            int row = idx / 28, c = idx % 28;
            float v;
            if (c < 8)       v = gp0[(size_t)(row0 + row) * 8 + c];
            else if (c < 20) v = gp1[(size_t)(row0 + row) * 12 + (c - 8)];
            else             v = gp2[(size_t)(row0 + row) * 8 + (c - 20)];
            gsh[idx] = v;
        }
    }

    __syncthreads();   // h/b2/gates visible; LDS read-only from here on

    f32x4 oA[2][2] = {}, oS[2][2] = {}, oB[2][2] = {};

#pragma unroll 1
    for (int p = 0; p < 12; ++p) {
        const int gi = p >> 2, e = p & 3;

        // W2 fragments for this pair: wave's 32 d x 64 h (4 b128 loads)
        f16x8 wf[2][2];
        const f16* w2 = W2T + (size_t)(gi * 4 + e) * 16384;
#pragma unroll
        for (int kk = 0; kk < 2; ++kk)
#pragma unroll
            for (int j = 0; j < 2; ++j)
                wf[kk][j] = *(const f16x8*)(w2 + (size_t)(wn2 + j * 16 + lrow) * 64 + kk * 32 + quad * 8);

        f32x4 eacc[2][2] = {};
#pragma unroll
        for (int kk = 0; kk < 2; ++kk) {
            f16x8 af[2];
#pragma unroll
            for (int i = 0; i < 2; ++i) {
                int rr = i * 16 + lrow;
                int slot = (e * 8 + kk * 4 + quad) ^ (rr & 7);
                af[i] = *(const f16x8*)(hls + gi * 8192 + rr * 256 + slot * 8);
            }
#pragma unroll
            for (int i = 0; i < 2; ++i)
#pragma unroll
                for (int j = 0; j < 2; ++j)
                    eacc[i][j] = __builtin_amdgcn_mfma_f32_16x16x32_f16(af[i], wf[kk][j], eacc[i][j], 0, 0, 0);
        }

        float bias[2];
#pragma unroll
        for (int j = 0; j < 2; ++j)
            bias[j] = b2s[gi * 1024 + e * 256 + wn2 + j * 16 + lrow];

#pragma unroll
        for (int i = 0; i < 2; ++i) {
#pragma unroll
            for (int r = 0; r < 4; ++r) {
                int row = i * 16 + quad * 4 + r;
                float ga = 0.f, gs = 0.f, gb = 0.f;
                if (gi == 0)      { ga = gsh[row * 28 + e];      gs = gsh[row * 28 + 8 + e]; }
                else if (gi == 1) { ga = gsh[row * 28 + 4 + e];  gs = gsh[row * 28 + 12 + e]; gb = gsh[row * 28 + 24 + e]; }
                else              { gs = gsh[row * 28 + 16 + e]; gb = gsh[row * 28 + 20 + e]; }
#pragma unroll
                for (int j = 0; j < 2; ++j) {
                    float v = fmaxf(eacc[i][j][r] + bias[j], 0.0f);
                    if (gi == 0)      { oA[i][j][r] += ga * v; oS[i][j][r] += gs * v; }
                    else if (gi == 1) { oA[i][j][r] += ga * v; oS[i][j][r] += gs * v; oB[i][j][r] += gb * v; }
                    else              { oS[i][j][r] += gs * v; oB[i][j][r] += gb * v; }
                }
            }
        }
    }

    // epilogue: write the three outputs
#pragma unroll
    for (int j = 0; j < 2; ++j) {
        int d = wn2 + j * 16 + lrow;
#pragma unroll
        for (int i = 0; i < 2; ++i) {
#pragma unroll
            for (int r = 0; r < 4; ++r) {
                int row = row0 + i * 16 + quad * 4 + r;
                out[((size_t)0 * BB + row) * 256 + d] = oA[i][j][r];
                out[((size_t)1 * BB + row) * 256 + d] = oS[i][j][r];
                out[((size_t)2 * BB + row) * 256 + d] = oB[i][j][r];
            }
        }
    }
}

// ---------------------------------------------------------------------------
extern "C" void kernel_launch(void* const* d_in, const int* in_sizes, int n_in,
                              void* d_out, int out_size, void* d_ws, size_t ws_size,
                              hipStream_t stream)
{
    (void)in_sizes; (void)n_in; (void)out_size; (void)ws_size;

    const float* xA  = (const float*)d_in[0];
    const float* xS  = (const float*)d_in[1];
    const float* xB  = (const float*)d_in[2];
    const float* W1A = (const float*)d_in[3];
    const float* b1A = (const float*)d_in[4];
    const float* W2A = (const float*)d_in[5];
    const float* b2A = (const float*)d_in[6];
    const float* W1S = (const float*)d_in[7];
    const float* b1S = (const float*)d_in[8];
    const float* W2S = (const float*)d_in[9];
    const float* b2S = (const float*)d_in[10];
    const float* W1B = (const float*)d_in[11];
    const float* b1B = (const float*)d_in[12];
    const float* W2B = (const float*)d_in[13];
    const float* b2B = (const float*)d_in[14];
    const float* WgA = (const float*)d_in[15];
    const float* bgA = (const float*)d_in[16];
    const float* WgB = (const float*)d_in[17];
    const float* bgB = (const float*)d_in[18];
    const float* WgS = (const float*)d_in[19];
    const float* bgS = (const float*)d_in[20];

    char* ws = (char*)d_ws;
    f16*   Wp   = (f16*)(ws);                       // 1,572,864 B
    f16*   W2T  = (f16*)(ws + 0x180000);            //   393,216 B
    f16*   Gp   = (f16*)(ws + 0x1E0000);            //    98,304 B
    f16*   hbuf = (f16*)(ws + 0x200000);            // 25,165,824 B
    float* gate = (float*)(ws + 0x200000 + 0x1800000); // 1,835,008 B

    pack_kernel<<<243, 256, 0, stream>>>(W1A, W1S, W1B, W2A, W2S, W2B,
                                         WgA, WgS, WgB, Wp, W2T, Gp);
    l1_kernel<<<dim3(2, 128, 3), 256, 0, stream>>>(
        xA, xS, xB, b1A, b1S, b1B, bgA, bgS, bgB,
        Wp, Gp, hbuf, gate);
    l2_kernel<<<512, 512, 65024, stream>>>(
        hbuf, W2T, b2A, b2S, b2B, gate, (float*)d_out);
}